// Round 3
// baseline (1012.522 us; speedup 1.0000x reference)
//
#include <hip/hip_runtime.h>

#define B_  256
#define T_  256
#define S_  20
#define U1  32
#define G1  128   // 4*U1
#define U2  24
#define G2  96    // 4*U2

__device__ __forceinline__ float fast_rcp(float x) { return __builtin_amdgcn_rcpf(x); }
__device__ __forceinline__ float sigmoidf_(float x) { return fast_rcp(1.0f + __expf(-x)); }
// tanh(x) = 1 - 2/(1+e^{2x}); saturates correctly at +-1 for large |x|
__device__ __forceinline__ float tanhf_fast(float x) { return 1.0f - 2.0f * fast_rcp(1.0f + __expf(2.0f * x)); }

// Inner LSTM: 64 rows per block, 4 waves per block. Wave w owns units
// [8w, 8w+8) of all 64 rows (lane = row): all 4 gates of a unit live on one
// lane, so the c/h update is local. Weights remain WAVE-UNIFORM (s_load
// broadcasts) because every lane of a wave touches the same column subset.
// h is exchanged via a double-buffered LDS array (stride 33 -> (lane+k)%32
// banks, conflict-free), ONE __syncthreads per step.
// Rationale: R1/R2 were ~1 wave/SIMD (grid 1024 waves) -> latency-bound at
// VALUBusy 22%. This keeps the same VALU work but 4x the waves.
template <bool WRITE_P>
__global__ __launch_bounds__(256, 4) void inner_kernel(
    const float* __restrict__ x,        // [B*T*S]
    const int*   __restrict__ lengths,  // [B]
    const float* __restrict__ Wi,       // [G1]
    const float* __restrict__ Ui,       // [U1*G1]
    const float* __restrict__ bi,       // [G1]
    const float* __restrict__ Wo,       // [U1*G2]
    const float* __restrict__ bo,       // [G2]
    float* __restrict__ outbuf)         // P [B*T*G2] or feats [B*T*U1]
{
    __shared__ float hbuf[2][64][33];
    const int lane = threadIdx.x & 63;
    const int w    = threadIdx.x >> 6;        // unit-group 0..3
    const int tile = blockIdx.x & 3;          // 64-wide t-tile within sequence
    const int b    = blockIdx.x >> 2;
    const int len  = lengths[b];
    if (tile * 64 >= len) return;             // whole block masked: uniform exit
                                              // (before any barrier)
    const int t = tile * 64 + lane;
    const int r = b * T_ + t;
    const bool active = (t < len);            // inactive lanes compute garbage
                                              // into their own row slot only;
                                              // stores are guarded below.
    const int uw = w * 8;

    const float* xp = x + (size_t)r * S_;
    float c[8];
#pragma unroll
    for (int j = 0; j < 8; ++j) c[j] = 0.0f;

    float xv = xp[0];
    int p = 0;
#pragma unroll 1
    for (int s = 0; s < S_; ++s) {
        const int sn = (s + 1 < S_) ? s + 1 : S_ - 1;
        const float xn = xp[sn];              // 1-step x prefetch

        float z[4][8];
#pragma unroll
        for (int g = 0; g < 4; ++g)
#pragma unroll
            for (int j = 0; j < 8; ++j)
                z[g][j] = bi[g * U1 + uw + j] + xv * Wi[g * U1 + uw + j];

        if (s > 0) {                          // h==0 at s==0 (uniform branch)
            float hk[U1];                     // hoist LDS reads: one lgkm wait
#pragma unroll
            for (int k = 0; k < U1; ++k) hk[k] = hbuf[p][lane][k];
#pragma unroll
            for (int k = 0; k < U1; ++k) {
                const float* Ur = Ui + k * G1;
#pragma unroll
                for (int g = 0; g < 4; ++g)
#pragma unroll
                    for (int j = 0; j < 8; ++j)
                        z[g][j] += hk[k] * Ur[g * U1 + uw + j];
            }
        }

#pragma unroll
        for (int j = 0; j < 8; ++j) {
            const float ig = sigmoidf_(z[0][j]);
            const float fg = sigmoidf_(z[1][j]);
            const float gg = tanhf_fast(z[2][j]);
            const float og = sigmoidf_(z[3][j]);
            c[j] = fg * c[j] + ig * gg;
            hbuf[p ^ 1][lane][uw + j] = og * tanhf_fast(c[j]);
        }
        __syncthreads();                      // 1 barrier/step (double buffer)
        p ^= 1;
        xv = xn;
    }

    if constexpr (WRITE_P) {
        if (active) {
            // P row = bo + h @ Wo, wave w computes cols [24w, 24w+24)
            float hk[U1];
#pragma unroll
            for (int k = 0; k < U1; ++k) hk[k] = hbuf[p][lane][k];
            float pa[U2];
#pragma unroll
            for (int j = 0; j < U2; ++j) pa[j] = bo[U2 * w + j];
#pragma unroll
            for (int k = 0; k < U1; ++k) {
                const float* Wr = Wo + k * G2 + U2 * w;
#pragma unroll
                for (int j = 0; j < U2; ++j) pa[j] += hk[k] * Wr[j];
            }
            float4* Pp = (float4*)(outbuf + (size_t)r * G2 + U2 * w); // 16B-aligned
#pragma unroll
            for (int j = 0; j < U2 / 4; ++j)
                Pp[j] = make_float4(pa[4 * j], pa[4 * j + 1], pa[4 * j + 2], pa[4 * j + 3]);
        }
    } else {
        if (active && w == 0) {
            float hk[U1];
#pragma unroll
            for (int k = 0; k < U1; ++k) hk[k] = hbuf[p][lane][k];
            float4* Fp = (float4*)(outbuf + (size_t)r * U1);
#pragma unroll
            for (int j = 0; j < U1 / 4; ++j)
                Fp[j] = make_float4(hk[4 * j], hk[4 * j + 1], hk[4 * j + 2], hk[4 * j + 3]);
        }
    }
}

// Outer LSTM + head: 1 wave per sequence b; lane u<24 owns unit u.
// Ring-3 prefetch of P rows (covers ~900cyc HBM latency vs ~300cyc step
// chain); z accumulation split into 2 partials to halve the serial FMA chain.
template <bool USE_P>
__global__ __launch_bounds__(64, 1) void outer_kernel(
    const float* __restrict__ buf,      // P [B*T*G2] or feats [B*T*U1]
    const int*   __restrict__ lengths,  // [B]
    const float* __restrict__ Wo,       // (only if !USE_P)
    const float* __restrict__ Uo,       // [U2*G2]
    const float* __restrict__ bo,       // (only if !USE_P)
    const float* __restrict__ Wd,       // [U2]
    const float* __restrict__ bd,       // [1]
    float* __restrict__ out)            // [B]
{
    const int b = blockIdx.x;
    const int lane = threadIdx.x;
    const int u = (lane < U2) ? lane : 0;

    float wu[4][U2];
#pragma unroll
    for (int g = 0; g < 4; ++g)
#pragma unroll
        for (int k = 0; k < U2; ++k)
            wu[g][k] = Uo[k * G2 + g * U2 + u];

    float wx[4][U1];
    float bz[4];
    if constexpr (!USE_P) {
#pragma unroll
        for (int g = 0; g < 4; ++g) {
            bz[g] = bo[g * U2 + u];
#pragma unroll
            for (int k = 0; k < U1; ++k)
                wx[g][k] = Wo[k * G2 + g * U2 + u];
        }
    }

    const int len = lengths[b];              // >= 1 by construction
    const int rowstride = USE_P ? G2 : U1;
    const float* Pb = buf + (size_t)b * T_ * rowstride;

    float cu = 0.0f, hu = 0.0f;

    float p0[4], p1[4], p2[4];
    if constexpr (USE_P) {
        const int t1 = (1 < len) ? 1 : len - 1;
        const int t2 = (2 < len) ? 2 : len - 1;
#pragma unroll
        for (int g = 0; g < 4; ++g) {
            p0[g] = Pb[g * U2 + u];
            p1[g] = Pb[(size_t)t1 * G2 + g * U2 + u];
            p2[g] = Pb[(size_t)t2 * G2 + g * U2 + u];
        }
    }

#pragma unroll 1
    for (int t = 0; t < len; ++t) {
        float pn[4];
        if constexpr (USE_P) {
            const int tn = (t + 3 < len) ? (t + 3) : (len - 1);
            const float* Ptn = Pb + (size_t)tn * G2;
#pragma unroll
            for (int g = 0; g < 4; ++g) pn[g] = Ptn[g * U2 + u];
        }

        float za[4], zb[4];
        if constexpr (USE_P) {
#pragma unroll
            for (int g = 0; g < 4; ++g) { za[g] = p0[g]; zb[g] = 0.0f; }
        } else {
#pragma unroll
            for (int g = 0; g < 4; ++g) { za[g] = bz[g]; zb[g] = 0.0f; }
            const float* Ft = Pb + (size_t)t * U1;
#pragma unroll
            for (int k = 0; k < U1; ++k) {
                const float fk = Ft[k];      // uniform address -> s_load
#pragma unroll
                for (int g = 0; g < 4; ++g) {
                    if (k & 1) zb[g] += fk * wx[g][k];
                    else       za[g] += fk * wx[g][k];
                }
            }
        }

        if (t > 0) {                         // uniform; h==0 at t==0
            float hk[U2];
#pragma unroll
            for (int k = 0; k < U2; ++k) hk[k] = __shfl(hu, k);
#pragma unroll
            for (int k = 0; k < U2 / 2; ++k)
#pragma unroll
                for (int g = 0; g < 4; ++g) za[g] += hk[k] * wu[g][k];
#pragma unroll
            for (int k = U2 / 2; k < U2; ++k)
#pragma unroll
                for (int g = 0; g < 4; ++g) zb[g] += hk[k] * wu[g][k];
        }

        const float ig = sigmoidf_(za[0] + zb[0]);
        const float fg = sigmoidf_(za[1] + zb[1]);
        const float gg = tanhf_fast(za[2] + zb[2]);
        const float og = sigmoidf_(za[3] + zb[3]);
        cu = fg * cu + ig * gg;
        hu = og * tanhf_fast(cu);

        if constexpr (USE_P) {
#pragma unroll
            for (int g = 0; g < 4; ++g) { p0[g] = p1[g]; p1[g] = p2[g]; p2[g] = pn[g]; }
        }
    }

    // dense sigmoid head
    float acc = bd[0];
#pragma unroll
    for (int k = 0; k < U2; ++k) acc += __shfl(hu, k) * Wd[k];
    if (lane == 0) out[b] = sigmoidf_(acc);
}

extern "C" void kernel_launch(void* const* d_in, const int* in_sizes, int n_in,
                              void* d_out, int out_size, void* d_ws, size_t ws_size,
                              hipStream_t stream) {
    const float* x       = (const float*)d_in[0];
    const int*   lengths = (const int*)  d_in[1];
    const float* Wi      = (const float*)d_in[2];
    const float* Ui      = (const float*)d_in[3];
    const float* bi      = (const float*)d_in[4];
    const float* Wo      = (const float*)d_in[5];
    const float* Uo      = (const float*)d_in[6];
    const float* bo      = (const float*)d_in[7];
    const float* Wd      = (const float*)d_in[8];
    const float* bd      = (const float*)d_in[9];
    float* out = (float*)d_out;

    const size_t P_BYTES = (size_t)B_ * T_ * G2 * sizeof(float);   // 25.2 MB

    if (ws_size >= P_BYTES) {
        float* P = (float*)d_ws;
        inner_kernel<true><<<dim3(B_ * T_ / 64), dim3(256), 0, stream>>>(
            x, lengths, Wi, Ui, bi, Wo, bo, P);
        outer_kernel<true><<<dim3(B_), dim3(64), 0, stream>>>(
            P, lengths, Wo, Uo, bo, Wd, bd, out);
    } else {
        float* F = (float*)d_ws;   // 8.4 MB feats fallback
        inner_kernel<false><<<dim3(B_ * T_ / 64), dim3(256), 0, stream>>>(
            x, lengths, Wi, Ui, bi, Wo, bo, F);
        outer_kernel<false><<<dim3(B_), dim3(64), 0, stream>>>(
            F, lengths, Wo, Uo, bo, Wd, bd, out);
    }
}

// Round 4
// 371.379 us; speedup vs baseline: 2.7264x; 2.7264x over previous
//
#include <hip/hip_runtime.h>

#define B_  256
#define T_  256
#define S_  20
#define U1  32
#define G1  128   // 4*U1
#define U2  24
#define G2  96    // 4*U2

__device__ __forceinline__ float fast_rcp(float x) { return __builtin_amdgcn_rcpf(x); }
__device__ __forceinline__ float sigmoidf_(float x) { return fast_rcp(1.0f + __expf(-x)); }
// tanh(x) = 1 - 2/(1+e^{2x}); saturates correctly at +-1 for large |x|
__device__ __forceinline__ float tanhf_fast(float x) { return 1.0f - 2.0f * fast_rcp(1.0f + __expf(2.0f * x)); }

// Inner LSTM: 64 rows/block (t-tile), 4 waves/block; wave w owns units
// [8w,8w+8) x all 4 gates (c/h update lane-local). Weight addresses are
// forced scalar via readfirstlane(w) -> s_load broadcasts, values live in
// SGPRs not VGPRs (R3 failure: VGPR=64 cap + non-scalarized weights ->
// 560 MB scratch spill traffic). launch_bounds(256,2): 256-VGPR cap, no
// spill; natural occupancy ~4-5 waves/SIMD hides s_load/LDS latency.
// h exchanged via double-buffered LDS (stride 33 -> conflict-free b32),
// one __syncthreads per step.
template <bool WRITE_P>
__global__ __launch_bounds__(256, 2) void inner_kernel(
    const float* __restrict__ x,        // [B*T*S]
    const int*   __restrict__ lengths,  // [B]
    const float* __restrict__ Wi,       // [G1]
    const float* __restrict__ Ui,       // [U1*G1]
    const float* __restrict__ bi,       // [G1]
    const float* __restrict__ Wo,       // [U1*G2]
    const float* __restrict__ bo,       // [G2]
    float* __restrict__ outbuf)         // P [B*T*G2] or feats [B*T*U1]
{
    __shared__ float hbuf[2][64][33];
    const int lane = threadIdx.x & 63;
    // wave id, forced into an SGPR so every weight address is scalar
    const int wv = __builtin_amdgcn_readfirstlane((int)(threadIdx.x >> 6));
    const int wg = wv * 8;                    // unit offset (scalar)
    const int wq = wv * U2;                   // P-col offset (scalar)
    const int tile = blockIdx.x & 3;
    const int b    = blockIdx.x >> 2;
    const int len  = lengths[b];
    if (tile * 64 >= len) return;             // whole-block masked: uniform exit
                                              // before any barrier
    const int t = tile * 64 + lane;
    const int r = b * T_ + t;
    const bool active = (t < len);            // inactive lanes compute garbage
                                              // in their own row slot only

    const float* xp = x + (size_t)r * S_;
    float c[8];
#pragma unroll
    for (int j = 0; j < 8; ++j) c[j] = 0.0f;

    float xv = xp[0];
    int p = 0;
#pragma unroll 1
    for (int s = 0; s < S_; ++s) {
        const int sn = (s + 1 < S_) ? s + 1 : S_ - 1;
        const float xn = xp[sn];              // 1-step x prefetch

        float z[4][8];
#pragma unroll
        for (int g = 0; g < 4; ++g)
#pragma unroll
            for (int j = 0; j < 8; ++j)
                z[g][j] = bi[g * U1 + wg + j] + xv * Wi[g * U1 + wg + j];

        if (s > 0) {                          // h==0 at s==0 (uniform branch)
            const float* hL = &hbuf[p][lane][0];
#pragma unroll
            for (int kk = 0; kk < 4; ++kk) {  // 8 h-values at a time: bounded regs
                float hk[8];
#pragma unroll
                for (int q = 0; q < 8; ++q) hk[q] = hL[kk * 8 + q];
#pragma unroll
                for (int q = 0; q < 8; ++q) {
                    const float* Ur = Ui + (kk * 8 + q) * G1 + wg;  // scalar addr
#pragma unroll
                    for (int g = 0; g < 4; ++g)
#pragma unroll
                        for (int j = 0; j < 8; ++j)
                            z[g][j] += hk[q] * Ur[g * U1 + j];
                }
            }
        }

#pragma unroll
        for (int j = 0; j < 8; ++j) {
            const float ig = sigmoidf_(z[0][j]);
            const float fg = sigmoidf_(z[1][j]);
            const float gg = tanhf_fast(z[2][j]);
            const float og = sigmoidf_(z[3][j]);
            c[j] = fg * c[j] + ig * gg;
            hbuf[p ^ 1][lane][wg + j] = og * tanhf_fast(c[j]);
        }
        __syncthreads();
        p ^= 1;
        xv = xn;
    }

    if constexpr (WRITE_P) {
        if (active) {
            // P row = bo + h @ Wo; wave w computes cols [24w, 24w+24)
            float pa[U2];
#pragma unroll
            for (int j = 0; j < U2; ++j) pa[j] = bo[wq + j];
            const float* hL = &hbuf[p][lane][0];
#pragma unroll
            for (int kk = 0; kk < 4; ++kk) {
                float hk[8];
#pragma unroll
                for (int q = 0; q < 8; ++q) hk[q] = hL[kk * 8 + q];
#pragma unroll
                for (int q = 0; q < 8; ++q) {
                    const float* Wr = Wo + (kk * 8 + q) * G2 + wq;  // scalar addr
#pragma unroll
                    for (int j = 0; j < U2; ++j) pa[j] += hk[q] * Wr[j];
                }
            }
            float4* Pp = (float4*)(outbuf + (size_t)r * G2 + wq);   // 16B-aligned
#pragma unroll
            for (int j = 0; j < U2 / 4; ++j)
                Pp[j] = make_float4(pa[4 * j], pa[4 * j + 1], pa[4 * j + 2], pa[4 * j + 3]);
        }
    } else {
        if (active && wv == 0) {
            float hk[U1];
#pragma unroll
            for (int k = 0; k < U1; ++k) hk[k] = hbuf[p][lane][k];
            float4* Fp = (float4*)(outbuf + (size_t)r * U1);
#pragma unroll
            for (int j = 0; j < U1 / 4; ++j)
                Fp[j] = make_float4(hk[4 * j], hk[4 * j + 1], hk[4 * j + 2], hk[4 * j + 3]);
        }
    }
}

// Outer LSTM + head (P path): 1 wave per sequence. Lane layout: lane = 32*half + sub;
// lanes sub<24 own unit sub; half 0 accumulates k=0..11, half 1 k=12..23,
// combined per step with one shfl_xor(32) -> halves the serial FMA chain.
// P staged through double-buffered LDS in 32-step chunks: 12 coalesced
// float4 loads issued per chunk, consumed 32 steps later -> HBM latency
// amortized to ~30 cyc/step instead of serializing ~900 cyc per row.
__global__ __launch_bounds__(64, 1) void outer_kernel_p(
    const float* __restrict__ P,        // [B*T*G2]
    const int*   __restrict__ lengths,  // [B]
    const float* __restrict__ Uo,       // [U2*G2]
    const float* __restrict__ Wd,       // [U2]
    const float* __restrict__ bd,       // [1]
    float* __restrict__ out)            // [B]
{
    __shared__ float pl[2][32 * G2];    // 24 KB
    const int b = blockIdx.x;
    const int lane = threadIdx.x;
    const int half = lane >> 5;
    const int sub  = lane & 31;
    const int u    = (sub < U2) ? sub : U2 - 1;

    float wu[4][12];
#pragma unroll
    for (int g = 0; g < 4; ++g)
#pragma unroll
        for (int kk = 0; kk < 12; ++kk)
            wu[g][kk] = Uo[(half * 12 + kk) * G2 + g * U2 + u];

    const int len = lengths[b];              // >= 1
    const float* Pb = P + (size_t)b * T_ * G2;

    // stage chunk 0
    float4 st[12];
    {
        const float4* gp = (const float4*)Pb;
#pragma unroll
        for (int i = 0; i < 12; ++i) st[i] = gp[lane + 64 * i];
        float4* lp = (float4*)&pl[0][0];
#pragma unroll
        for (int i = 0; i < 12; ++i) lp[lane + 64 * i] = st[i];
    }

    const int nch = (len + 31) >> 5;
    float cu = 0.0f, hu = 0.0f;

#pragma unroll 1
    for (int ch = 0; ch < nch; ++ch) {
        if (ch + 1 < nch) {                  // issue next chunk's loads now;
            const float4* gp = (const float4*)(Pb + (size_t)(ch + 1) * 32 * G2);
#pragma unroll
            for (int i = 0; i < 12; ++i) st[i] = gp[lane + 64 * i];
        }                                    // vmcnt wait lands at the ds_write below
        const int pb = ch & 1;
        const int rem = len - ch * 32;
        const int tmax = (rem < 32) ? rem : 32;
#pragma unroll 1
        for (int tt = 0; tt < tmax; ++tt) {
            const float* row = &pl[pb][tt * G2];
            float z0[4], z1[4];
#pragma unroll
            for (int g = 0; g < 4; ++g) {
                z0[g] = (half == 0) ? row[g * U2 + u] : 0.0f;
                z1[g] = 0.0f;
            }
            if (ch * 32 + tt > 0) {          // uniform; h==0 at t==0
                float hk[12];
#pragma unroll
                for (int kk = 0; kk < 12; ++kk) hk[kk] = __shfl(hu, half * 12 + kk);
#pragma unroll
                for (int kk = 0; kk < 12; ++kk)
#pragma unroll
                    for (int g = 0; g < 4; ++g) {
                        if (kk & 1) z1[g] += hk[kk] * wu[g][kk];
                        else        z0[g] += hk[kk] * wu[g][kk];
                    }
            }
            float z[4];
#pragma unroll
            for (int g = 0; g < 4; ++g) {
                const float sgl = z0[g] + z1[g];
                z[g] = sgl + __shfl_xor(sgl, 32);   // combine the two k-halves
            }
            const float ig = sigmoidf_(z[0]);
            const float fg = sigmoidf_(z[1]);
            const float gg = tanhf_fast(z[2]);
            const float og = sigmoidf_(z[3]);
            cu = fg * cu + ig * gg;
            hu = og * tanhf_fast(cu);
        }
        if (ch + 1 < nch) {
            float4* lp = (float4*)&pl[(ch + 1) & 1][0];
#pragma unroll
            for (int i = 0; i < 12; ++i) lp[lane + 64 * i] = st[i];
        }
    }

    // dense sigmoid head
    float acc = bd[0];
#pragma unroll
    for (int k = 0; k < U2; ++k) acc += __shfl(hu, k) * Wd[k];
    if (lane == 0) out[b] = sigmoidf_(acc);
}

// Fallback outer (feats path, ws too small for P): R2 version, known-correct.
__global__ __launch_bounds__(64, 1) void outer_kernel_f(
    const float* __restrict__ feats,    // [B*T*U1]
    const int*   __restrict__ lengths,
    const float* __restrict__ Wo,       // [U1*G2]
    const float* __restrict__ Uo,       // [U2*G2]
    const float* __restrict__ bo,       // [G2]
    const float* __restrict__ Wd,
    const float* __restrict__ bd,
    float* __restrict__ out)
{
    const int b = blockIdx.x;
    const int lane = threadIdx.x;
    const int u = (lane < U2) ? lane : 0;

    float wu[4][U2];
#pragma unroll
    for (int g = 0; g < 4; ++g)
#pragma unroll
        for (int k = 0; k < U2; ++k)
            wu[g][k] = Uo[k * G2 + g * U2 + u];

    float wx[4][U1];
    float bz[4];
#pragma unroll
    for (int g = 0; g < 4; ++g) {
        bz[g] = bo[g * U2 + u];
#pragma unroll
        for (int k = 0; k < U1; ++k)
            wx[g][k] = Wo[k * G2 + g * U2 + u];
    }

    const int len = lengths[b];
    const float* Fb = feats + (size_t)b * T_ * U1;
    float cu = 0.0f, hu = 0.0f;

#pragma unroll 1
    for (int t = 0; t < len; ++t) {
        float z[4];
#pragma unroll
        for (int g = 0; g < 4; ++g) z[g] = bz[g];
        const float* Ft = Fb + (size_t)t * U1;
#pragma unroll
        for (int k = 0; k < U1; ++k) {
            const float fk = Ft[k];
#pragma unroll
            for (int g = 0; g < 4; ++g) z[g] += fk * wx[g][k];
        }
        if (t > 0) {
            float hk[U2];
#pragma unroll
            for (int k = 0; k < U2; ++k) hk[k] = __shfl(hu, k);
#pragma unroll
            for (int k = 0; k < U2; ++k)
#pragma unroll
                for (int g = 0; g < 4; ++g) z[g] += hk[k] * wu[g][k];
        }
        const float ig = sigmoidf_(z[0]);
        const float fg = sigmoidf_(z[1]);
        const float gg = tanhf_fast(z[2]);
        const float og = sigmoidf_(z[3]);
        cu = fg * cu + ig * gg;
        hu = og * tanhf_fast(cu);
    }

    float acc = bd[0];
#pragma unroll
    for (int k = 0; k < U2; ++k) acc += __shfl(hu, k) * Wd[k];
    if (lane == 0) out[b] = sigmoidf_(acc);
}

extern "C" void kernel_launch(void* const* d_in, const int* in_sizes, int n_in,
                              void* d_out, int out_size, void* d_ws, size_t ws_size,
                              hipStream_t stream) {
    const float* x       = (const float*)d_in[0];
    const int*   lengths = (const int*)  d_in[1];
    const float* Wi      = (const float*)d_in[2];
    const float* Ui      = (const float*)d_in[3];
    const float* bi      = (const float*)d_in[4];
    const float* Wo      = (const float*)d_in[5];
    const float* Uo      = (const float*)d_in[6];
    const float* bo      = (const float*)d_in[7];
    const float* Wd      = (const float*)d_in[8];
    const float* bd      = (const float*)d_in[9];
    float* out = (float*)d_out;

    const size_t P_BYTES = (size_t)B_ * T_ * G2 * sizeof(float);   // 25.2 MB

    if (ws_size >= P_BYTES) {
        float* P = (float*)d_ws;
        inner_kernel<true><<<dim3(B_ * T_ / 64), dim3(256), 0, stream>>>(
            x, lengths, Wi, Ui, bi, Wo, bo, P);
        outer_kernel_p<<<dim3(B_), dim3(64), 0, stream>>>(
            P, lengths, Uo, Wd, bd, out);
    } else {
        float* F = (float*)d_ws;   // 8.4 MB feats fallback
        inner_kernel<false><<<dim3(B_ * T_ / 64), dim3(256), 0, stream>>>(
            x, lengths, Wi, Ui, bi, Wo, bo, F);
        outer_kernel_f<<<dim3(B_), dim3(64), 0, stream>>>(
            F, lengths, Wo, Uo, bo, Wd, bd, out);
    }
}

// Round 5
// 234.241 us; speedup vs baseline: 4.3226x; 1.5855x over previous
//
#include <hip/hip_runtime.h>

#define B_  256
#define T_  256
#define S_  20
#define U1  32
#define G1  128   // 4*U1
#define U2  24
#define G2  96    // 4*U2

typedef __attribute__((ext_vector_type(8))) short short8;   // 8 bf16 = 4 VGPRs
typedef __attribute__((ext_vector_type(4))) float f32x4;    // MFMA acc

__device__ __forceinline__ float fast_rcp(float x) { return __builtin_amdgcn_rcpf(x); }
__device__ __forceinline__ float sigmoidf_(float x) { return fast_rcp(1.0f + __expf(-x)); }
__device__ __forceinline__ float tanhf_fast(float x) { return 1.0f - 2.0f * fast_rcp(1.0f + __expf(2.0f * x)); }

// round-to-nearest-even f32 -> bf16
__device__ __forceinline__ unsigned short f2bf(float a) {
    unsigned int u = __float_as_uint(a);
    u += 0x7FFFu + ((u >> 16) & 1u);
    return (unsigned short)(u >> 16);
}
__device__ __forceinline__ unsigned int pack2bf(float a, float b) {
    unsigned int ua = __float_as_uint(a); ua += 0x7FFFu + ((ua >> 16) & 1u);
    unsigned int ub = __float_as_uint(b); ub += 0x7FFFu + ((ub >> 16) & 1u);
    return (ua >> 16) | (ub & 0xFFFF0000u);
}
union frag_u { short8 v; unsigned int u[4]; };

// Inner LSTM via MFMA (bf16 inputs, fp32 accumulate).
// One wave = 16 rows (t's) x all 32 units. Z[16x128] = H[16x32] @ Ui[32x128]
// as 8x mfma_f32_16x16x32_bf16 (K=32==U1: ONE mfma per 16-col tile per step).
// Ui lives in 32 VGPRs/lane as B-fragments, loaded ONCE -> zero in-loop
// weight traffic (R2/R4 re-streamed 4KB/step/wave through K$ = the 3x stall).
// C-layout: col=lane&15, row=quad*4+reg -> gate g=tile>>1, unit=16*(tile&1)+n:
// all 4 gates of a unit on the SAME lane -> c/h update is pure per-lane VALU.
// h round-trips LDS per-wave (bf16, stride 40 ushorts: b128 reads 2-way = free),
// DS in-order within a wave -> NO barriers anywhere.
template <bool WRITE_P>
__global__ __launch_bounds__(256, 2) void inner_kernel(
    const float* __restrict__ x,        // [B*T*S]
    const int*   __restrict__ lengths,  // [B]
    const float* __restrict__ Wi,       // [G1]
    const float* __restrict__ Ui,       // [U1*G1]
    const float* __restrict__ bi,       // [G1]
    const float* __restrict__ Wo,       // [U1*G2]
    const float* __restrict__ bo,       // [G2]
    float* __restrict__ outbuf)         // P [B*T*G2] or feats [B*T*U1]
{
    __shared__ unsigned short hb[4][16][40];    // per-wave h tile, bf16
    const int lane = threadIdx.x & 63;
    const int w = __builtin_amdgcn_readfirstlane((int)(threadIdx.x >> 6));
    const int q = lane >> 4;                    // quad
    const int n = lane & 15;                    // col-in-tile / A-row
    const int tile = blockIdx.x & 3;            // 64-wide t-tile
    const int b    = blockIdx.x >> 2;
    const int len  = lengths[b];
    const int wt0  = tile * 64 + w * 16;        // wave's first t
    if (wt0 >= len) return;                     // wave-uniform exit (no barriers)

    // ---- load Ui as B-fragments: B[k=q*8+j][col=16*tt+n], once ----
    frag_u Bui[8];
#pragma unroll
    for (int tt = 0; tt < 8; ++tt)
#pragma unroll
        for (int k2 = 0; k2 < 4; ++k2) {
            const float e0 = Ui[(8 * q + 2 * k2) * G1 + 16 * tt + n];
            const float e1 = Ui[(8 * q + 2 * k2 + 1) * G1 + 16 * tt + n];
            Bui[tt].u[k2] = pack2bf(e0, e1);
        }

    // per-lane bias/Wi for cols 16*tt+n (fp32, exact x-path)
    float bi_l[8], Wi_l[8];
#pragma unroll
    for (int tt = 0; tt < 8; ++tt) { bi_l[tt] = bi[16 * tt + n]; Wi_l[tt] = Wi[16 * tt + n]; }

    const float* xq = x + (size_t)(b * T_ + wt0 + 4 * q) * S_;  // rows 4q..4q+3
    float c[2][4];
#pragma unroll
    for (int uh = 0; uh < 2; ++uh)
#pragma unroll
        for (int r = 0; r < 4; ++r) c[uh][r] = 0.0f;

    float xr[4], xn[4];
#pragma unroll
    for (int r = 0; r < 4; ++r) xr[r] = xq[r * S_];

#pragma unroll 1
    for (int s = 0; s < S_; ++s) {
        const int sn = (s + 1 < S_) ? s + 1 : S_ - 1;
#pragma unroll
        for (int r = 0; r < 4; ++r) xn[r] = xq[r * S_ + sn];   // prefetch

        f32x4 acc[8];
#pragma unroll
        for (int tt = 0; tt < 8; ++tt)
#pragma unroll
            for (int r = 0; r < 4; ++r)
                acc[tt][r] = bi_l[tt] + xr[r] * Wi_l[tt];

        if (s > 0) {   // h==0 at s==0 (uniform)
            const short8 A = *(const short8*)&hb[w][n][8 * q];  // ds_read_b128
#pragma unroll
            for (int tt = 0; tt < 8; ++tt)
                acc[tt] = __builtin_amdgcn_mfma_f32_16x16x32_bf16(A, Bui[tt].v, acc[tt], 0, 0, 0);
        }

#pragma unroll
        for (int uh = 0; uh < 2; ++uh)
#pragma unroll
            for (int r = 0; r < 4; ++r) {
                const float iv = sigmoidf_(acc[0 + uh][r]);
                const float fv = sigmoidf_(acc[2 + uh][r]);
                const float gv = tanhf_fast(acc[4 + uh][r]);
                const float ov = sigmoidf_(acc[6 + uh][r]);
                c[uh][r] = fv * c[uh][r] + iv * gv;
                hb[w][4 * q + r][n + 16 * uh] = f2bf(ov * tanhf_fast(c[uh][r]));
            }
#pragma unroll
        for (int r = 0; r < 4; ++r) xr[r] = xn[r];
    }

    if constexpr (WRITE_P) {
        // P tile = bo + h @ Wo : 6 more MFMAs with Wo fragments
        frag_u Bwo[6];
#pragma unroll
        for (int tt = 0; tt < 6; ++tt)
#pragma unroll
            for (int k2 = 0; k2 < 4; ++k2) {
                const float e0 = Wo[(8 * q + 2 * k2) * G2 + 16 * tt + n];
                const float e1 = Wo[(8 * q + 2 * k2 + 1) * G2 + 16 * tt + n];
                Bwo[tt].u[k2] = pack2bf(e0, e1);
            }
        const short8 A = *(const short8*)&hb[w][n][8 * q];
        f32x4 accp[6];
#pragma unroll
        for (int tt = 0; tt < 6; ++tt) {
            const float bv = bo[16 * tt + n];
#pragma unroll
            for (int r = 0; r < 4; ++r) accp[tt][r] = bv;
            accp[tt] = __builtin_amdgcn_mfma_f32_16x16x32_bf16(A, Bwo[tt].v, accp[tt], 0, 0, 0);
        }
#pragma unroll
        for (int r = 0; r < 4; ++r) {
            const int t_row = wt0 + 4 * q + r;
            if (t_row < len) {
                float* Pr = outbuf + (size_t)(b * T_ + t_row) * G2 + n;
#pragma unroll
                for (int tt = 0; tt < 6; ++tt) Pr[16 * tt] = accp[tt][r];
            }
        }
    } else {
#pragma unroll
        for (int r = 0; r < 4; ++r) {
            const int t_row = wt0 + 4 * q + r;
            if (t_row < len) {
                float* Fr = outbuf + (size_t)(b * T_ + t_row) * U1;
#pragma unroll
                for (int uh = 0; uh < 2; ++uh)
                    Fr[n + 16 * uh] = __uint_as_float((unsigned)hb[w][4 * q + r][n + 16 * uh] << 16);
            }
        }
    }
}

// Outer LSTM + head: 1 wave/seq, lane u<24 owns unit u (4 gates local).
// h broadcast via v_readlane -> SGPR (VALU latency) instead of ds_bpermute
// (~120+ cyc LDS latency on the serial chain -- the constant ~145us across
// R1/R2/R4 designs). FMA then uses the SGPR operand directly. fp32 throughout.
__global__ __launch_bounds__(64, 1) void outer_kernel_p(
    const float* __restrict__ P,        // [B*T*G2]
    const int*   __restrict__ lengths,  // [B]
    const float* __restrict__ Uo,       // [U2*G2]
    const float* __restrict__ Wd,       // [U2]
    const float* __restrict__ bd,       // [1]
    float* __restrict__ out)            // [B]
{
    const int b = blockIdx.x;
    const int lane = threadIdx.x;
    const int u = (lane < U2) ? lane : U2 - 1;

    float wu[4][U2];
#pragma unroll
    for (int g = 0; g < 4; ++g)
#pragma unroll
        for (int k = 0; k < U2; ++k)
            wu[g][k] = Uo[k * G2 + g * U2 + u];

    const int len = lengths[b];          // >= 1
    const float* Pb = P + (size_t)b * T_ * G2;

    float cu = 0.0f, hu = 0.0f;
    float p0[4], p1[4], p2[4];
    {
        const int t1 = (1 < len) ? 1 : len - 1;
        const int t2 = (2 < len) ? 2 : len - 1;
#pragma unroll
        for (int g = 0; g < 4; ++g) {
            p0[g] = Pb[g * U2 + u];
            p1[g] = Pb[(size_t)t1 * G2 + g * U2 + u];
            p2[g] = Pb[(size_t)t2 * G2 + g * U2 + u];
        }
    }

#pragma unroll 1
    for (int t = 0; t < len; ++t) {
        float pn[4];
        const int tn = (t + 3 < len) ? (t + 3) : (len - 1);
        const float* Ptn = Pb + (size_t)tn * G2;
#pragma unroll
        for (int g = 0; g < 4; ++g) pn[g] = Ptn[g * U2 + u];

        float za[4], zb[4];
#pragma unroll
        for (int g = 0; g < 4; ++g) { za[g] = p0[g]; zb[g] = 0.0f; }

        if (t > 0) {                     // uniform; h==0 at t==0
#pragma unroll
            for (int k = 0; k < U2; ++k) {
                const float hk = __int_as_float(
                    __builtin_amdgcn_readlane(__float_as_int(hu), k));  // -> SGPR
#pragma unroll
                for (int g = 0; g < 4; ++g) {
                    if (k & 1) zb[g] += hk * wu[g][k];
                    else       za[g] += hk * wu[g][k];
                }
            }
        }

        const float ig = sigmoidf_(za[0] + zb[0]);
        const float fg = sigmoidf_(za[1] + zb[1]);
        const float gg = tanhf_fast(za[2] + zb[2]);
        const float og = sigmoidf_(za[3] + zb[3]);
        cu = fg * cu + ig * gg;
        hu = og * tanhf_fast(cu);

#pragma unroll
        for (int g = 0; g < 4; ++g) { p0[g] = p1[g]; p1[g] = p2[g]; p2[g] = pn[g]; }
    }

    float acc = bd[0];
#pragma unroll
    for (int k = 0; k < U2; ++k)
        acc += __int_as_float(__builtin_amdgcn_readlane(__float_as_int(hu), k)) * Wd[k];
    if (lane == 0) out[b] = sigmoidf_(acc);
}

// Fallback outer (feats path): folds Wo matvec per step; readlane broadcast.
__global__ __launch_bounds__(64, 1) void outer_kernel_f(
    const float* __restrict__ feats,    // [B*T*U1]
    const int*   __restrict__ lengths,
    const float* __restrict__ Wo,       // [U1*G2]
    const float* __restrict__ Uo,       // [U2*G2]
    const float* __restrict__ bo,       // [G2]
    const float* __restrict__ Wd,
    const float* __restrict__ bd,
    float* __restrict__ out)
{
    const int b = blockIdx.x;
    const int lane = threadIdx.x;
    const int u = (lane < U2) ? lane : U2 - 1;

    float wu[4][U2], wx[4][U1], bz[4];
#pragma unroll
    for (int g = 0; g < 4; ++g) {
        bz[g] = bo[g * U2 + u];
#pragma unroll
        for (int k = 0; k < U2; ++k) wu[g][k] = Uo[k * G2 + g * U2 + u];
#pragma unroll
        for (int k = 0; k < U1; ++k) wx[g][k] = Wo[k * G2 + g * U2 + u];
    }

    const int len = lengths[b];
    const float* Fb = feats + (size_t)b * T_ * U1;
    float cu = 0.0f, hu = 0.0f;

#pragma unroll 1
    for (int t = 0; t < len; ++t) {
        float z[4];
#pragma unroll
        for (int g = 0; g < 4; ++g) z[g] = bz[g];
        const float* Ft = Fb + (size_t)t * U1;
#pragma unroll
        for (int k = 0; k < U1; ++k) {
            const float fk = Ft[k];
#pragma unroll
            for (int g = 0; g < 4; ++g) z[g] += fk * wx[g][k];
        }
        if (t > 0) {
#pragma unroll
            for (int k = 0; k < U2; ++k) {
                const float hk = __int_as_float(
                    __builtin_amdgcn_readlane(__float_as_int(hu), k));
#pragma unroll
                for (int g = 0; g < 4; ++g) z[g] += hk * wu[g][k];
            }
        }
        const float ig = sigmoidf_(z[0]);
        const float fg = sigmoidf_(z[1]);
        const float gg = tanhf_fast(z[2]);
        const float og = sigmoidf_(z[3]);
        cu = fg * cu + ig * gg;
        hu = og * tanhf_fast(cu);
    }

    float acc = bd[0];
#pragma unroll
    for (int k = 0; k < U2; ++k)
        acc += __int_as_float(__builtin_amdgcn_readlane(__float_as_int(hu), k)) * Wd[k];
    if (lane == 0) out[b] = sigmoidf_(acc);
}

extern "C" void kernel_launch(void* const* d_in, const int* in_sizes, int n_in,
                              void* d_out, int out_size, void* d_ws, size_t ws_size,
                              hipStream_t stream) {
    const float* x       = (const float*)d_in[0];
    const int*   lengths = (const int*)  d_in[1];
    const float* Wi      = (const float*)d_in[2];
    const float* Ui      = (const float*)d_in[3];
    const float* bi      = (const float*)d_in[4];
    const float* Wo      = (const float*)d_in[5];
    const float* Uo      = (const float*)d_in[6];
    const float* bo      = (const float*)d_in[7];
    const float* Wd      = (const float*)d_in[8];
    const float* bd      = (const float*)d_in[9];
    float* out = (float*)d_out;

    const size_t P_BYTES = (size_t)B_ * T_ * G2 * sizeof(float);   // 25.2 MB

    if (ws_size >= P_BYTES) {
        float* P = (float*)d_ws;
        inner_kernel<true><<<dim3(B_ * T_ / 64), dim3(256), 0, stream>>>(
            x, lengths, Wi, Ui, bi, Wo, bo, P);
        outer_kernel_p<<<dim3(B_), dim3(64), 0, stream>>>(
            P, lengths, Uo, Wd, bd, out);
    } else {
        float* F = (float*)d_ws;   // 8.4 MB feats fallback
        inner_kernel<false><<<dim3(B_ * T_ / 64), dim3(256), 0, stream>>>(
            x, lengths, Wi, Ui, bi, Wo, bo, F);
        outer_kernel_f<<<dim3(B_), dim3(64), 0, stream>>>(
            F, lengths, Wo, Uo, bo, Wd, bd, out);
    }
}